// Round 2
// baseline (191.204 us; speedup 1.0000x reference)
//
#include <hip/hip_runtime.h>
#include <cstdint>

#define LX 16384
#define NB 16
#define LT 64
#define TPB 4                 // l-tiles per block; grid.x = LX/(LT*TPB) = 64
#define HALO 8
#define XI (LT + 2*HALO)      // 80 staged positions
#define XPD 36                // x row pitch in dwords (144 B, 16B-aligned; chunk-rotated)

typedef __attribute__((ext_vector_type(2))) _Float16 h2;
typedef __attribute__((ext_vector_type(8))) _Float16 h8;
typedef __attribute__((ext_vector_type(4))) unsigned u4;
typedef __attribute__((ext_vector_type(4))) float f4;

static __device__ __forceinline__ h2 u2h(unsigned u) {
    union { unsigned u; h2 h; } v; v.u = u; return v.h;
}
static __device__ __forceinline__ unsigned h2u(h2 h) {
    union { h2 h; unsigned u; } v; v.h = h; return v.u;
}
static __device__ __forceinline__ unsigned pkrtz(float a, float b) {
    auto r = __builtin_amdgcn_cvt_pkrtz(a, b);        // __fp16 ext_vector(2)
    union { decltype(r) h; unsigned u; } v; v.h = r;
    return v.u;
}

// raw barriers: __syncthreads() drains vmcnt(0) and would kill the x prefetch.
#define BAR_LGKM() do { asm volatile("s_waitcnt lgkmcnt(0)" ::: "memory"); \
                        __builtin_amdgcn_s_barrier();                      \
                        asm volatile("" ::: "memory"); } while (0)
#define BAR_RAW()  do { asm volatile("" ::: "memory");                     \
                        __builtin_amdgcn_s_barrier();                      \
                        asm volatile("" ::: "memory"); } while (0)

// ---------------- kernel 0: prep weights into ws (all f16) ----------------
// ws: A2 f16[64][192] @0 (24576 B)  A2[o*192 + tap*64 + c] = weight[o][c][tap]
//   | beff f32[6] @24576
//   | wcg u32[14*256] @24608 (14336 B): combined offset/mask conv weights,
//     pre-fragmented for mfma_f32_16x16x32_f16 A-operand.
//     step s (=kk2), lane ln, dword d:  m=ln&15, q=ln>>4, j=s>>1,
//     c=(s&1)*32+q*8+2d : packs (W[m][c][j], W[m][c+1][j]),
//     W[m][c][j] = pw[m][c]*dw[c][j] (m<3: off branch, 3..5: msk, else 0)
__global__ void prep_kernel(const float* __restrict__ weight,
                            const float* __restrict__ b_off_pw, const float* __restrict__ w_off_pw,
                            const float* __restrict__ b_off_dw,
                            const float* __restrict__ b_msk_pw, const float* __restrict__ w_msk_pw,
                            const float* __restrict__ b_msk_dw,
                            const float* __restrict__ w_off_dw, const float* __restrict__ w_msk_dw,
                            short* __restrict__ A2, float* __restrict__ beff,
                            unsigned* __restrict__ wcg) {
    int bid = blockIdx.x;
    int t = threadIdx.x;
    if (bid < 48) {
        int idx = bid * 256 + t;                  // 0..12287 : A2[o][tap*64+c]
        int o = idx / 192;
        int rem = idx - o * 192;
        int tap = rem >> 6, c = rem & 63;
        union { _Float16 h; short s; } v;
        v.h = (_Float16)weight[o * 192 + c * 3 + tap];
        A2[idx] = v.s;
    } else {
        // combined offset/mask conv weights, A-fragment order
        int lane = t >> 2, d = t & 3;
        int m = lane & 15, qq = lane >> 4;
        #pragma unroll
        for (int s = 0; s < 14; ++s) {
            int j = s >> 1;
            int c = (s & 1) * 32 + qq * 8 + 2 * d;
            float w0 = 0.f, w1 = 0.f;
            if (m < 3) {
                w0 = w_off_pw[m * 64 + c]     * w_off_dw[c * 7 + j];
                w1 = w_off_pw[m * 64 + c + 1] * w_off_dw[(c + 1) * 7 + j];
            } else if (m < 6) {
                w0 = w_msk_pw[(m - 3) * 64 + c]     * w_msk_dw[c * 7 + j];
                w1 = w_msk_pw[(m - 3) * 64 + c + 1] * w_msk_dw[(c + 1) * 7 + j];
            }
            wcg[s * 256 + t] = pkrtz(w0, w1);
        }
        if (t < 6) {
            int br = t / 3, m3 = t % 3;
            const float* pw = br ? w_msk_pw : w_off_pw;
            const float* bd = br ? b_msk_dw : b_off_dw;
            const float* bp = br ? b_msk_pw : b_off_pw;
            float s = bp[m3];
            for (int c = 0; c < 64; ++c) s += pw[m3 * 64 + c] * bd[c];
            beff[t] = s;
        }
    }
}

// ---------------- main fused kernel ----------------
// Each block owns TPB=4 consecutive l-tiles. A2 + combined conv weights staged
// once per block (weights live in 14 A-fragments = 56 VGPRs); the x tile for
// t+1 is prefetched into registers during tile t's compute and ds-written
// between tiles. Phase2 (offset/mask conv) is now an MFMA over K=448; its
// outputs stay wave-local (registers + shfl), so no phase2->phase3 barrier.
__launch_bounds__(256, 4)
__global__ void deform_main(const float* __restrict__ x,
                            const float* __restrict__ bias,
                            const short* __restrict__ A2,
                            const float* __restrict__ beff,
                            const unsigned* __restrict__ wcg,
                            float* __restrict__ out) {
    // x tile f16 [i][c], c-pairs as dwords; 8-dword chunks rotated by row: phys = (chunk + i) & 3
    __shared__ __align__(16) unsigned xdw[XI * XPD];        // 11520 B
    // A2 staged in LDS, XOR-swizzled: phys_dw = row*96 + (dw ^ ((row&7)<<2))
    __shared__ __align__(16) unsigned A2l[6144];            // 24576 B
    __shared__ float bias_l[64];                            // 256 B
    __shared__ float beff_l[8];                             // 32 B
    // total 36384 B -> 4 blocks/CU

    const int t = threadIdx.x;
    const int lane = t & 63;
    const int wv = t >> 6;
    const int r = lane & 15, q = lane >> 4;
    const int lbase = blockIdx.x * (LT * TPB);
    const int b = blockIdx.y;
    const float* xb = x + (size_t)b * (64 * LX);

    // register staging for the next x tile (issue-early / write-late)
    f4 rx0[3], rx1[3];

    auto issue_x = [&](int l0v) {
        #pragma unroll
        for (int s = 0; s < 3; ++s) {
            int p = t + 256 * s;
            rx0[s] = (f4){0.f, 0.f, 0.f, 0.f};
            rx1[s] = (f4){0.f, 0.f, 0.f, 0.f};
            if (p < 640) {
                int cp = p & 31, up = p >> 5;
                int g4 = l0v - HALO + up * 4;
                if ((unsigned)g4 < (unsigned)LX) {
                    rx0[s] = *(const f4*)(xb + (size_t)(2 * cp) * LX + g4);
                    rx1[s] = *(const f4*)(xb + (size_t)(2 * cp + 1) * LX + g4);
                }
            }
        }
    };
    auto write_x = [&]() {
        #pragma unroll
        for (int s = 0; s < 3; ++s) {
            int p = t + 256 * s;
            if (p < 640) {
                int cp = p & 31, up = p >> 5;
                #pragma unroll
                for (int d = 0; d < 4; ++d) {
                    int i = up * 4 + d;
                    int pc = ((cp >> 3) + i) & 3;
                    xdw[i * XPD + pc * 8 + (cp & 7)] = pkrtz(rx0[s][d], rx1[s][d]);
                }
            }
        }
    };

    // ---- prologue: issue x tile 0, stage block-constant data, write tile 0,
    //      issue x tile 1 ----
    issue_x(lbase);
    {
        const u4* A2g4 = (const u4*)A2;          // 1536 u4, coalesced 16B/lane
        #pragma unroll
        for (int s = 0; s < 6; ++s) {
            int idx = t + 256 * s;               // 0..1535
            int row = idx / 24;
            int g = idx - row * 24;
            int pdw = row * 96 + ((g * 4) ^ ((row & 7) << 2));
            *(u4*)&A2l[pdw] = A2g4[idx];
        }
    }
    // combined conv weight A-fragments: once per block, kept in registers
    u4 wfr[14];
    {
        const u4* wc4 = (const u4*)wcg;
        #pragma unroll
        for (int s = 0; s < 14; ++s) wfr[s] = wc4[s * 64 + lane];
    }
    if (t < 64) bias_l[t] = bias[t];
    if (t < 6)  beff_l[t] = beff[t];
    write_x();                                   // waits vmcnt for tile-0 loads
    issue_x(lbase + LT);                         // tile-1 loads fly during tile 0
    BAR_LGKM();

    #pragma unroll
    for (int tt = 0; tt < TPB; ++tt) {
        const int l0 = lbase + tt * LT;

        // ---- phase 2: offset/mask conv as MFMA, M=16(6 used) K=448 N=16/wave ----
        // D row m (0..2 off, 3..5 msk), col l = wv*16 + (lane&15).
        unsigned mywp = 0; int myli = 0;
        {
            f4 acc2 = {0.f, 0.f, 0.f, 0.f};
            const int irow = wv * 16 + r + 5;            // + j
            #pragma unroll
            for (int s = 0; s < 14; ++s) {
                const int j = s >> 1, half = s & 1;
                const int i = irow + j;
                const int chunk = half * 2 + (q >> 1);
                const int pd = i * XPD + (((chunk + i) & 3) << 3) + ((q & 1) << 2);
                union { u4 u; h8 h; } bx; bx.u = *(const u4*)&xdw[pd];
                union { u4 u; h8 h; } ax; ax.u = wfr[s];
                acc2 = __builtin_amdgcn_mfma_f32_16x16x32_f16(ax.h, bx.h, acc2, 0, 0, 0);
            }
            // epilogue: gather (off_k, msk_k) per lane q=k (k=0..2), col r
            float b0 = __shfl(acc2[0], r);           // off0: q0.e0
            float b1 = __shfl(acc2[1], r);           // off1: q0.e1
            float b2 = __shfl(acc2[2], r);           // off2: q0.e2
            float m0 = __shfl(acc2[3], r);           // msk0: q0.e3
            float m1 = __shfl(acc2[0], 16 + r);      // msk1: q1.e0
            float m2 = __shfl(acc2[1], 16 + r);      // msk2: q1.e1
            if (q < 3) {
                const int k = q, l = wv * 16 + r;
                float off = (k == 0 ? b0 : k == 1 ? b1 : b2) + beff_l[k];
                float z   = (k == 0 ? m0 : k == 1 ? m1 : m2) + beff_l[3 + k];
                float msk = 1.0f / (1.0f + __expf(-z));
                float p = (float)(l0 + l - 1 + k) + off;   // ref op order
                float fl = floorf(p);
                int i0 = (int)fl, i1 = i0 + 1;
                float fr = p - fl;
                int li0 = i0 - l0 + HALO, li1 = li0 + 1;
                float w0 = (((unsigned)i0 < (unsigned)LX) && ((unsigned)li0 < (unsigned)XI)) ? (1.0f - fr) * msk : 0.0f;
                float w1 = (((unsigned)i1 < (unsigned)LX) && ((unsigned)li1 < (unsigned)XI)) ? fr * msk : 0.0f;
                li0 = min(max(li0, 0), XI - 2);            // rows li0, li0+1 both staged
                mywp = pkrtz(w0, w1);
                myli = li0;
            }
        }
        // no barrier: kl data is wave-local (shfl), xdw/A2l are read-only here

        // ---- phase 3: out[o][l] = W2[o][(tap,c)] @ xs[(tap,c)][l], M=64 K=192 N=64 ----
        {
            const int lcol = wv * 16 + r;
            unsigned wpt[3]; int lit[3];
            #pragma unroll
            for (int tap = 0; tap < 3; ++tap) {
                wpt[tap] = __shfl(mywp, tap * 16 + r);
                lit[tap] = __shfl(myli, tap * 16 + r);
            }
            f4 acc[4];
            #pragma unroll
            for (int mt = 0; mt < 4; ++mt) acc[mt] = (f4){0.f, 0.f, 0.f, 0.f};
            const int sw = (r & 7) << 2;
            #pragma unroll
            for (int kk = 0; kk < 6; ++kk) {
                const int tap = kk >> 1;
                unsigned wp = wpt[tap];
                unsigned w00 = __builtin_amdgcn_perm(wp, wp, 0x01000100u);  // (w0,w0)
                unsigned w11 = __builtin_amdgcn_perm(wp, wp, 0x03020302u);  // (w1,w1)
                int li0 = lit[tap];
                int cp0 = ((kk & 1) << 4) + (q << 2);      // dword idx {0,4,...,28}
                int chunkL = cp0 >> 3;
                int o0 = li0 * XPD + ((((chunkL + li0) & 3) << 3) | (cp0 & 7));
                int o1 = (li0 + 1) * XPD + ((((chunkL + li0 + 1) & 3) << 3) | (cp0 & 7));
                u4 r0 = *(const u4*)&xdw[o0];
                u4 r1 = *(const u4*)&xdw[o1];
                u4 xs;
                #pragma unroll
                for (int d = 0; d < 4; ++d)
                    xs[d] = h2u(u2h(r0[d]) * u2h(w00) + u2h(r1[d]) * u2h(w11));
                union { u4 u; h8 h; } bfr; bfr.u = xs;
                #pragma unroll
                for (int mt = 0; mt < 4; ++mt) {
                    union { u4 u; h8 h; } af;
                    af.u = *(const u4*)&A2l[(mt * 16 + r) * 96 + ((kk * 16 + q * 4) ^ sw)];
                    acc[mt] = __builtin_amdgcn_mfma_f32_16x16x32_f16(af.h, bfr.h, acc[mt], 0, 0, 0);
                }
            }
            #pragma unroll
            for (int mt = 0; mt < 4; ++mt) {
                int ob = mt * 16 + 4 * q;     // D row o = mt*16 + 4q + e, col l = lcol
                float* op = out + ((size_t)b * 64 + ob) * LX + l0 + lcol;
                #pragma unroll
                for (int e = 0; e < 4; ++e)
                    op[(size_t)e * LX] = acc[mt][e] + bias_l[ob + e];
            }
        }

        // ---- inter-tile: publish prefetched x tile t+1, issue loads for t+2 ----
        if (tt < TPB - 1) {
            BAR_RAW();                         // all xdw readers of tile tt done
            write_x();                         // waits vmcnt only for rx regs
            if (tt + 2 < TPB) issue_x(lbase + (tt + 2) * LT);
            BAR_LGKM();                        // new xdw visible for next phase 2
        }
    }
}

extern "C" void kernel_launch(void* const* d_in, const int* in_sizes, int n_in,
                              void* d_out, int out_size, void* d_ws, size_t ws_size,
                              hipStream_t stream) {
    const float* x        = (const float*)d_in[0];
    const float* w_off_dw = (const float*)d_in[1];
    const float* b_off_dw = (const float*)d_in[2];
    const float* w_off_pw = (const float*)d_in[3];
    const float* b_off_pw = (const float*)d_in[4];
    const float* w_msk_dw = (const float*)d_in[5];
    const float* b_msk_dw = (const float*)d_in[6];
    const float* w_msk_pw = (const float*)d_in[7];
    const float* b_msk_pw = (const float*)d_in[8];
    const float* weight   = (const float*)d_in[9];
    const float* bias     = (const float*)d_in[10];
    float* out = (float*)d_out;

    short*    A2   = (short*)d_ws;                     // 24576 B
    float*    beff = (float*)((char*)d_ws + 24576);    // 24 B (padded to 32)
    unsigned* wcg  = (unsigned*)((char*)d_ws + 24608); // 14336 B

    hipLaunchKernelGGL(prep_kernel, dim3(49), dim3(256), 0, stream,
                       weight, b_off_pw, w_off_pw, b_off_dw, b_msk_pw, w_msk_pw, b_msk_dw,
                       w_off_dw, w_msk_dw, A2, beff, wcg);
    hipLaunchKernelGGL(deform_main, dim3(LX / (LT * TPB), NB), dim3(256), 0, stream,
                       x, bias, A2, beff, wcg, out);
}

// Round 3
// 169.625 us; speedup vs baseline: 1.1272x; 1.1272x over previous
//
#include <hip/hip_runtime.h>
#include <cstdint>

#define LX 16384
#define NB 16
#define LT 64
#define TPB 4                 // l-tiles per block; grid.x = LX/(LT*TPB) = 64
#define HALO 8
#define XI (LT + 2*HALO)      // 80 staged positions
#define XPD 36                // x row pitch in dwords (144 B, 16B-aligned; chunk-rotated)

typedef __attribute__((ext_vector_type(2))) _Float16 h2;
typedef __attribute__((ext_vector_type(8))) _Float16 h8;
typedef __attribute__((ext_vector_type(4))) unsigned u4;
typedef __attribute__((ext_vector_type(4))) float f4;

static __device__ __forceinline__ h2 u2h(unsigned u) {
    union { unsigned u; h2 h; } v; v.u = u; return v.h;
}
static __device__ __forceinline__ unsigned h2u(h2 h) {
    union { h2 h; unsigned u; } v; v.h = h; return v.u;
}
static __device__ __forceinline__ unsigned pkrtz(float a, float b) {
    auto r = __builtin_amdgcn_cvt_pkrtz(a, b);        // __fp16 ext_vector(2)
    union { decltype(r) h; unsigned u; } v; v.h = r;
    return v.u;
}

// raw barriers: __syncthreads() drains vmcnt(0) and would kill the x prefetch.
#define BAR_LGKM() do { asm volatile("s_waitcnt lgkmcnt(0)" ::: "memory"); \
                        __builtin_amdgcn_s_barrier();                      \
                        asm volatile("" ::: "memory"); } while (0)
#define BAR_RAW()  do { asm volatile("" ::: "memory");                     \
                        __builtin_amdgcn_s_barrier();                      \
                        asm volatile("" ::: "memory"); } while (0)

// ---------------- kernel 0: prep weights into ws (all f16) ----------------
// ws: A2 f16[64][192] @0 (24576 B)  A2[o*192 + tap*64 + c] = weight[o][c][tap]
//   | beff f32[6] @24576
//   | wcg u32[14*256] @24608 (14336 B): combined offset/mask conv weights,
//     pre-fragmented for mfma_f32_16x16x32_f16 A-operand.
//     step s, thread t (lane=t>>2, d=t&3): m=lane&15, q=lane>>4, j=s>>1,
//     c=(s&1)*32+q*8+2d : packs (W[m][c][j], W[m][c+1][j]),
//     W[m][c][j] = pw[m][c]*dw[c][j] (m<3: off branch, 3..5: msk, else 0)
__global__ void prep_kernel(const float* __restrict__ weight,
                            const float* __restrict__ b_off_pw, const float* __restrict__ w_off_pw,
                            const float* __restrict__ b_off_dw,
                            const float* __restrict__ b_msk_pw, const float* __restrict__ w_msk_pw,
                            const float* __restrict__ b_msk_dw,
                            const float* __restrict__ w_off_dw, const float* __restrict__ w_msk_dw,
                            short* __restrict__ A2, float* __restrict__ beff,
                            unsigned* __restrict__ wcg) {
    int bid = blockIdx.x;
    int t = threadIdx.x;
    if (bid < 48) {
        int idx = bid * 256 + t;                  // 0..12287 : A2[o][tap*64+c]
        int o = idx / 192;
        int rem = idx - o * 192;
        int tap = rem >> 6, c = rem & 63;
        union { _Float16 h; short s; } v;
        v.h = (_Float16)weight[o * 192 + c * 3 + tap];
        A2[idx] = v.s;
    } else {
        // combined offset/mask conv weights, A-fragment order
        int lane = t >> 2, d = t & 3;
        int m = lane & 15, qq = lane >> 4;
        #pragma unroll
        for (int s = 0; s < 14; ++s) {
            int j = s >> 1;
            int c = (s & 1) * 32 + qq * 8 + 2 * d;
            float w0 = 0.f, w1 = 0.f;
            if (m < 3) {
                w0 = w_off_pw[m * 64 + c]     * w_off_dw[c * 7 + j];
                w1 = w_off_pw[m * 64 + c + 1] * w_off_dw[(c + 1) * 7 + j];
            } else if (m < 6) {
                w0 = w_msk_pw[(m - 3) * 64 + c]     * w_msk_dw[c * 7 + j];
                w1 = w_msk_pw[(m - 3) * 64 + c + 1] * w_msk_dw[(c + 1) * 7 + j];
            }
            wcg[s * 256 + t] = pkrtz(w0, w1);
        }
        if (t < 6) {
            int br = t / 3, m3 = t % 3;
            const float* pw = br ? w_msk_pw : w_off_pw;
            const float* bd = br ? b_msk_dw : b_off_dw;
            const float* bp = br ? b_msk_pw : b_off_pw;
            float s = bp[m3];
            for (int c = 0; c < 64; ++c) s += pw[m3 * 64 + c] * bd[c];
            beff[t] = s;
        }
    }
}

// ---------------- main fused kernel ----------------
// Each block owns TPB=4 consecutive l-tiles. A2 staged once per block; the
// combined conv weight A-fragments are re-loaded from L2 PER TILE (pointer
// laundered via asm so LICM can't hoist them into a kernel-length live range
// -- round 2 held them in 56 regs for the whole kernel and the allocator
// spilled to scratch: FETCH_SIZE +82MB, WRITE_SIZE +45MB). The x tile for
// t+1 is prefetched into registers during tile t's compute and ds-written
// between tiles. Phase-2 outputs stay wave-local (registers + shfl), so
// there is no phase2->phase3 barrier.
__launch_bounds__(256, 4)
__global__ void deform_main(const float* __restrict__ x,
                            const float* __restrict__ bias,
                            const short* __restrict__ A2,
                            const float* __restrict__ beff,
                            const unsigned* __restrict__ wcg,
                            float* __restrict__ out) {
    // x tile f16 [i][c], c-pairs as dwords; 8-dword chunks rotated by row: phys = (chunk + i) & 3
    __shared__ __align__(16) unsigned xdw[XI * XPD];        // 11520 B
    // A2 staged in LDS, XOR-swizzled: phys_dw = row*96 + (dw ^ ((row&7)<<2))
    __shared__ __align__(16) unsigned A2l[6144];            // 24576 B
    __shared__ float bias_l[64];                            // 256 B
    __shared__ float beff_l[8];                             // 32 B
    // total 36384 B -> 4 blocks/CU

    const int t = threadIdx.x;
    const int lane = t & 63;
    const int wv = t >> 6;
    const int r = lane & 15, q = lane >> 4;
    const int lbase = blockIdx.x * (LT * TPB);
    const int b = blockIdx.y;
    const float* xb = x + (size_t)b * (64 * LX);

    // register staging for the next x tile (issue-early / write-late)
    f4 rx0[3], rx1[3];

    auto issue_x = [&](int l0v) {
        #pragma unroll
        for (int s = 0; s < 3; ++s) {
            int p = t + 256 * s;
            rx0[s] = (f4){0.f, 0.f, 0.f, 0.f};
            rx1[s] = (f4){0.f, 0.f, 0.f, 0.f};
            if (p < 640) {
                int cp = p & 31, up = p >> 5;
                int g4 = l0v - HALO + up * 4;
                if ((unsigned)g4 < (unsigned)LX) {
                    rx0[s] = *(const f4*)(xb + (size_t)(2 * cp) * LX + g4);
                    rx1[s] = *(const f4*)(xb + (size_t)(2 * cp + 1) * LX + g4);
                }
            }
        }
    };
    auto write_x = [&]() {
        #pragma unroll
        for (int s = 0; s < 3; ++s) {
            int p = t + 256 * s;
            if (p < 640) {
                int cp = p & 31, up = p >> 5;
                #pragma unroll
                for (int d = 0; d < 4; ++d) {
                    int i = up * 4 + d;
                    int pc = ((cp >> 3) + i) & 3;
                    xdw[i * XPD + pc * 8 + (cp & 7)] = pkrtz(rx0[s][d], rx1[s][d]);
                }
            }
        }
    };

    // ---- prologue: issue x tile 0, stage block-constant data, write tile 0,
    //      issue x tile 1 ----
    issue_x(lbase);
    {
        const u4* A2g4 = (const u4*)A2;          // 1536 u4, coalesced 16B/lane
        #pragma unroll
        for (int s = 0; s < 6; ++s) {
            int idx = t + 256 * s;               // 0..1535
            int row = idx / 24;
            int g = idx - row * 24;
            int pdw = row * 96 + ((g * 4) ^ ((row & 7) << 2));
            *(u4*)&A2l[pdw] = A2g4[idx];
        }
    }
    if (t < 64) bias_l[t] = bias[t];
    if (t < 6)  beff_l[t] = beff[t];
    write_x();                                   // waits vmcnt for tile-0 loads
    issue_x(lbase + LT);                         // tile-1 loads fly during tile 0
    BAR_LGKM();

    #pragma unroll
    for (int tt = 0; tt < TPB; ++tt) {
        const int l0 = lbase + tt * LT;

        // ---- per-tile A-fragment reload from L2 (short live range, no spill).
        // Pointer laundered so the 14 loads cannot be hoisted/CSE'd across tiles.
        const u4* wcp = (const u4*)wcg;
        asm volatile("" : "+s"(wcp));
        u4 wfr[14];
        #pragma unroll
        for (int s = 0; s < 14; ++s) wfr[s] = wcp[s * 64 + lane];

        // ---- phase 2: offset/mask conv as MFMA, M=16(6 used) K=448 N=16/wave ----
        // D row m (0..2 off, 3..5 msk), col l = wv*16 + (lane&15).
        unsigned mywp = 0; int myli = 0;
        {
            f4 acc2 = {0.f, 0.f, 0.f, 0.f};
            const int irow = wv * 16 + r + 5;            // + j
            #pragma unroll
            for (int s = 0; s < 14; ++s) {
                const int j = s >> 1, half = s & 1;
                const int i = irow + j;
                const int chunk = half * 2 + (q >> 1);
                const int pd = i * XPD + (((chunk + i) & 3) << 3) + ((q & 1) << 2);
                union { u4 u; h8 h; } bx; bx.u = *(const u4*)&xdw[pd];
                union { u4 u; h8 h; } ax; ax.u = wfr[s];
                acc2 = __builtin_amdgcn_mfma_f32_16x16x32_f16(ax.h, bx.h, acc2, 0, 0, 0);
            }
            // epilogue: gather (off_k, msk_k) per lane q=k (k=0..2), col r
            float b0 = __shfl(acc2[0], r);           // off0: q0.e0
            float b1 = __shfl(acc2[1], r);           // off1: q0.e1
            float b2 = __shfl(acc2[2], r);           // off2: q0.e2
            float m0 = __shfl(acc2[3], r);           // msk0: q0.e3
            float m1 = __shfl(acc2[0], 16 + r);      // msk1: q1.e0
            float m2 = __shfl(acc2[1], 16 + r);      // msk2: q1.e1
            if (q < 3) {
                const int k = q, l = wv * 16 + r;
                float off = (k == 0 ? b0 : k == 1 ? b1 : b2) + beff_l[k];
                float z   = (k == 0 ? m0 : k == 1 ? m1 : m2) + beff_l[3 + k];
                float msk = 1.0f / (1.0f + __expf(-z));
                float p = (float)(l0 + l - 1 + k) + off;   // ref op order
                float fl = floorf(p);
                int i0 = (int)fl, i1 = i0 + 1;
                float fr = p - fl;
                int li0 = i0 - l0 + HALO, li1 = li0 + 1;
                float w0 = (((unsigned)i0 < (unsigned)LX) && ((unsigned)li0 < (unsigned)XI)) ? (1.0f - fr) * msk : 0.0f;
                float w1 = (((unsigned)i1 < (unsigned)LX) && ((unsigned)li1 < (unsigned)XI)) ? fr * msk : 0.0f;
                li0 = min(max(li0, 0), XI - 2);            // rows li0, li0+1 both staged
                mywp = pkrtz(w0, w1);
                myli = li0;
            }
        }
        // no barrier: kl data is wave-local (shfl), xdw/A2l are read-only here

        // ---- phase 3: out[o][l] = W2[o][(tap,c)] @ xs[(tap,c)][l], M=64 K=192 N=64 ----
        {
            const int lcol = wv * 16 + r;
            unsigned wpt[3]; int lit[3];
            #pragma unroll
            for (int tap = 0; tap < 3; ++tap) {
                wpt[tap] = __shfl(mywp, tap * 16 + r);
                lit[tap] = __shfl(myli, tap * 16 + r);
            }
            f4 acc[4];
            #pragma unroll
            for (int mt = 0; mt < 4; ++mt) acc[mt] = (f4){0.f, 0.f, 0.f, 0.f};
            const int sw = (r & 7) << 2;
            #pragma unroll
            for (int kk = 0; kk < 6; ++kk) {
                const int tap = kk >> 1;
                unsigned wp = wpt[tap];
                unsigned w00 = __builtin_amdgcn_perm(wp, wp, 0x01000100u);  // (w0,w0)
                unsigned w11 = __builtin_amdgcn_perm(wp, wp, 0x03020302u);  // (w1,w1)
                int li0 = lit[tap];
                int cp0 = ((kk & 1) << 4) + (q << 2);      // dword idx {0,4,...,28}
                int chunkL = cp0 >> 3;
                int o0 = li0 * XPD + ((((chunkL + li0) & 3) << 3) | (cp0 & 7));
                int o1 = (li0 + 1) * XPD + ((((chunkL + li0 + 1) & 3) << 3) | (cp0 & 7));
                u4 r0 = *(const u4*)&xdw[o0];
                u4 r1 = *(const u4*)&xdw[o1];
                u4 xs;
                #pragma unroll
                for (int d = 0; d < 4; ++d)
                    xs[d] = h2u(u2h(r0[d]) * u2h(w00) + u2h(r1[d]) * u2h(w11));
                union { u4 u; h8 h; } bfr; bfr.u = xs;
                #pragma unroll
                for (int mt = 0; mt < 4; ++mt) {
                    union { u4 u; h8 h; } af;
                    af.u = *(const u4*)&A2l[(mt * 16 + r) * 96 + ((kk * 16 + q * 4) ^ sw)];
                    acc[mt] = __builtin_amdgcn_mfma_f32_16x16x32_f16(af.h, bfr.h, acc[mt], 0, 0, 0);
                }
            }
            #pragma unroll
            for (int mt = 0; mt < 4; ++mt) {
                int ob = mt * 16 + 4 * q;     // D row o = mt*16 + 4q + e, col l = lcol
                float* op = out + ((size_t)b * 64 + ob) * LX + l0 + lcol;
                #pragma unroll
                for (int e = 0; e < 4; ++e)
                    op[(size_t)e * LX] = acc[mt][e] + bias_l[ob + e];
            }
        }

        // ---- inter-tile: publish prefetched x tile t+1, issue loads for t+2 ----
        if (tt < TPB - 1) {
            BAR_RAW();                         // all xdw readers of tile tt done
            write_x();                         // waits vmcnt only for rx regs
            if (tt + 2 < TPB) issue_x(lbase + (tt + 2) * LT);
            BAR_LGKM();                        // new xdw visible for next phase 2
        }
    }
}

extern "C" void kernel_launch(void* const* d_in, const int* in_sizes, int n_in,
                              void* d_out, int out_size, void* d_ws, size_t ws_size,
                              hipStream_t stream) {
    const float* x        = (const float*)d_in[0];
    const float* w_off_dw = (const float*)d_in[1];
    const float* b_off_dw = (const float*)d_in[2];
    const float* w_off_pw = (const float*)d_in[3];
    const float* b_off_pw = (const float*)d_in[4];
    const float* w_msk_dw = (const float*)d_in[5];
    const float* b_msk_dw = (const float*)d_in[6];
    const float* w_msk_pw = (const float*)d_in[7];
    const float* b_msk_pw = (const float*)d_in[8];
    const float* weight   = (const float*)d_in[9];
    const float* bias     = (const float*)d_in[10];
    float* out = (float*)d_out;

    short*    A2   = (short*)d_ws;                     // 24576 B
    float*    beff = (float*)((char*)d_ws + 24576);    // 24 B (padded to 32)
    unsigned* wcg  = (unsigned*)((char*)d_ws + 24608); // 14336 B

    hipLaunchKernelGGL(prep_kernel, dim3(49), dim3(256), 0, stream,
                       weight, b_off_pw, w_off_pw, b_off_dw, b_msk_pw, w_msk_pw, b_msk_dw,
                       w_off_dw, w_msk_dw, A2, beff, wcg);
    hipLaunchKernelGGL(deform_main, dim3(LX / (LT * TPB), NB), dim3(256), 0, stream,
                       x, bias, A2, beff, wcg, out);
}

// Round 4
// 165.610 us; speedup vs baseline: 1.1545x; 1.0242x over previous
//
#include <hip/hip_runtime.h>
#include <cstdint>

#define LX 16384
#define NB 16
#define LT 64
#define TPB 4                 // l-tiles per block; grid.x = LX/(LT*TPB) = 64
#define HALO 8
#define XI (LT + 2*HALO)      // 80 staged positions
#define XPD 36                // x row pitch in dwords (144 B, 16B-aligned; chunk-rotated)

typedef __attribute__((ext_vector_type(2))) _Float16 h2;
typedef __attribute__((ext_vector_type(8))) _Float16 h8;
typedef __attribute__((ext_vector_type(4))) unsigned u4;
typedef __attribute__((ext_vector_type(4))) float f4;

static __device__ __forceinline__ h2 u2h(unsigned u) {
    union { unsigned u; h2 h; } v; v.u = u; return v.h;
}
static __device__ __forceinline__ unsigned h2u(h2 h) {
    union { h2 h; unsigned u; } v; v.h = h; return v.u;
}
static __device__ __forceinline__ unsigned pkrtz(float a, float b) {
    auto r = __builtin_amdgcn_cvt_pkrtz(a, b);        // __fp16 ext_vector(2)
    union { decltype(r) h; unsigned u; } v; v.h = r;
    return v.u;
}

// raw barriers: __syncthreads() drains vmcnt(0) and would kill the x prefetch.
#define BAR_LGKM() do { asm volatile("s_waitcnt lgkmcnt(0)" ::: "memory"); \
                        __builtin_amdgcn_s_barrier();                      \
                        asm volatile("" ::: "memory"); } while (0)
#define BAR_RAW()  do { asm volatile("" ::: "memory");                     \
                        __builtin_amdgcn_s_barrier();                      \
                        asm volatile("" ::: "memory"); } while (0)

// ---------------- kernel 0: prep weights into ws (all f16) ----------------
// ws: A2 f16[64][192] @0 (24576 B)  A2[o*192 + tap*64 + c] = weight[o][c][tap]
//   | beff f32[6] @24576
//   | wcg u32[14*256] @24608 (14336 B): combined offset/mask conv weights,
//     pre-fragmented for mfma_f32_16x16x32_f16 A-operand.
//     step s, thread t (lane=t>>2, d=t&3): m=lane&15, q=lane>>4, j=s>>1,
//     c=(s&1)*32+q*8+2d : packs (W[m][c][j], W[m][c+1][j]),
//     W[m][c][j] = pw[m][c]*dw[c][j] (m<3: off branch, 3..5: msk, else 0)
__global__ void prep_kernel(const float* __restrict__ weight,
                            const float* __restrict__ b_off_pw, const float* __restrict__ w_off_pw,
                            const float* __restrict__ b_off_dw,
                            const float* __restrict__ b_msk_pw, const float* __restrict__ w_msk_pw,
                            const float* __restrict__ b_msk_dw,
                            const float* __restrict__ w_off_dw, const float* __restrict__ w_msk_dw,
                            short* __restrict__ A2, float* __restrict__ beff,
                            unsigned* __restrict__ wcg) {
    int bid = blockIdx.x;
    int t = threadIdx.x;
    if (bid < 48) {
        int idx = bid * 256 + t;                  // 0..12287 : A2[o][tap*64+c]
        int o = idx / 192;
        int rem = idx - o * 192;
        int tap = rem >> 6, c = rem & 63;
        union { _Float16 h; short s; } v;
        v.h = (_Float16)weight[o * 192 + c * 3 + tap];
        A2[idx] = v.s;
    } else {
        // combined offset/mask conv weights, A-fragment order
        int lane = t >> 2, d = t & 3;
        int m = lane & 15, qq = lane >> 4;
        #pragma unroll
        for (int s = 0; s < 14; ++s) {
            int j = s >> 1;
            int c = (s & 1) * 32 + qq * 8 + 2 * d;
            float w0 = 0.f, w1 = 0.f;
            if (m < 3) {
                w0 = w_off_pw[m * 64 + c]     * w_off_dw[c * 7 + j];
                w1 = w_off_pw[m * 64 + c + 1] * w_off_dw[(c + 1) * 7 + j];
            } else if (m < 6) {
                w0 = w_msk_pw[(m - 3) * 64 + c]     * w_msk_dw[c * 7 + j];
                w1 = w_msk_pw[(m - 3) * 64 + c + 1] * w_msk_dw[(c + 1) * 7 + j];
            }
            wcg[s * 256 + t] = pkrtz(w0, w1);
        }
        if (t < 6) {
            int br = t / 3, m3 = t % 3;
            const float* pw = br ? w_msk_pw : w_off_pw;
            const float* bd = br ? b_msk_dw : b_off_dw;
            const float* bp = br ? b_msk_pw : b_off_pw;
            float s = bp[m3];
            for (int c = 0; c < 64; ++c) s += pw[m3 * 64 + c] * bd[c];
            beff[t] = s;
        }
    }
}

// ---------------- main fused kernel ----------------
// Each block owns TPB=4 consecutive l-tiles. A2 staged once per block; the
// combined conv weight A-fragments are re-loaded from L2 PER TILE (pointer
// laundered via asm so LICM can't hoist them into a kernel-length live range).
// Register live-range dovetail (round-4 fix): the x-tile prefetch rx0/rx1
// (24 regs) is issued at the START OF PHASE 3, not at the inter-tile
// boundary, so it is never live concurrently with wfr (56 regs, phase-2
// only). Round 3 overlapped them -> unified VGPR demand ~130 > 128 budget
// (launch_bounds 256,4) -> ~14 dword/thread scratch spill (+14.5 MB on both
// FETCH_SIZE and WRITE_SIZE). Phase-2 outputs stay wave-local (regs + shfl),
// so there is no phase2->phase3 barrier.
__launch_bounds__(256, 4)
__global__ void deform_main(const float* __restrict__ x,
                            const float* __restrict__ bias,
                            const short* __restrict__ A2,
                            const float* __restrict__ beff,
                            const unsigned* __restrict__ wcg,
                            float* __restrict__ out) {
    // x tile f16 [i][c], c-pairs as dwords; 8-dword chunks rotated by row: phys = (chunk + i) & 3
    __shared__ __align__(16) unsigned xdw[XI * XPD];        // 11520 B
    // A2 staged in LDS, XOR-swizzled: phys_dw = row*96 + (dw ^ ((row&7)<<2))
    __shared__ __align__(16) unsigned A2l[6144];            // 24576 B
    __shared__ float bias_l[64];                            // 256 B
    __shared__ float beff_l[8];                             // 32 B
    // total 36384 B -> 4 blocks/CU

    const int t = threadIdx.x;
    const int lane = t & 63;
    const int wv = t >> 6;
    const int r = lane & 15, q = lane >> 4;
    const int lbase = blockIdx.x * (LT * TPB);
    const int b = blockIdx.y;
    const float* xb = x + (size_t)b * (64 * LX);

    // register staging for the next x tile (issue in phase 3 / write at tile end)
    f4 rx0[3], rx1[3];

    auto issue_x = [&](int l0v) {
        #pragma unroll
        for (int s = 0; s < 3; ++s) {
            int p = t + 256 * s;
            rx0[s] = (f4){0.f, 0.f, 0.f, 0.f};
            rx1[s] = (f4){0.f, 0.f, 0.f, 0.f};
            if (p < 640) {
                int cp = p & 31, up = p >> 5;
                int g4 = l0v - HALO + up * 4;
                if ((unsigned)g4 < (unsigned)LX) {
                    rx0[s] = *(const f4*)(xb + (size_t)(2 * cp) * LX + g4);
                    rx1[s] = *(const f4*)(xb + (size_t)(2 * cp + 1) * LX + g4);
                }
            }
        }
    };
    auto write_x = [&]() {
        #pragma unroll
        for (int s = 0; s < 3; ++s) {
            int p = t + 256 * s;
            if (p < 640) {
                int cp = p & 31, up = p >> 5;
                #pragma unroll
                for (int d = 0; d < 4; ++d) {
                    int i = up * 4 + d;
                    int pc = ((cp >> 3) + i) & 3;
                    xdw[i * XPD + pc * 8 + (cp & 7)] = pkrtz(rx0[s][d], rx1[s][d]);
                }
            }
        }
    };

    // ---- prologue: issue x tile 0, stage block-constant data, write tile 0 ----
    issue_x(lbase);
    {
        const u4* A2g4 = (const u4*)A2;          // 1536 u4, coalesced 16B/lane
        #pragma unroll
        for (int s = 0; s < 6; ++s) {
            int idx = t + 256 * s;               // 0..1535
            int row = idx / 24;
            int g = idx - row * 24;
            int pdw = row * 96 + ((g * 4) ^ ((row & 7) << 2));
            *(u4*)&A2l[pdw] = A2g4[idx];
        }
    }
    if (t < 64) bias_l[t] = bias[t];
    if (t < 6)  beff_l[t] = beff[t];
    write_x();                                   // waits vmcnt for tile-0 loads
    BAR_LGKM();

    #pragma unroll
    for (int tt = 0; tt < TPB; ++tt) {
        const int l0 = lbase + tt * LT;

        // ---- per-tile A-fragment reload from L2 (short live range, no spill).
        // Pointer laundered so the 14 loads cannot be hoisted/CSE'd across tiles.
        const u4* wcp = (const u4*)wcg;
        asm volatile("" : "+s"(wcp));
        u4 wfr[14];
        #pragma unroll
        for (int s = 0; s < 14; ++s) wfr[s] = wcp[s * 64 + lane];

        // ---- phase 2: offset/mask conv as MFMA, M=16(6 used) K=448 N=16/wave ----
        // D row m (0..2 off, 3..5 msk), col l = wv*16 + (lane&15).
        // Two accumulator chains (7 deep each) halve the serial MFMA latency.
        unsigned mywp = 0; int myli = 0;
        {
            f4 acc2a = {0.f, 0.f, 0.f, 0.f};
            f4 acc2b = {0.f, 0.f, 0.f, 0.f};
            const int irow = wv * 16 + r + 5;            // + j
            #pragma unroll
            for (int s = 0; s < 14; ++s) {
                const int j = s >> 1, half = s & 1;
                const int i = irow + j;
                const int chunk = half * 2 + (q >> 1);
                const int pd = i * XPD + (((chunk + i) & 3) << 3) + ((q & 1) << 2);
                union { u4 u; h8 h; } bx; bx.u = *(const u4*)&xdw[pd];
                union { u4 u; h8 h; } ax; ax.u = wfr[s];
                if (s & 1)
                    acc2b = __builtin_amdgcn_mfma_f32_16x16x32_f16(ax.h, bx.h, acc2b, 0, 0, 0);
                else
                    acc2a = __builtin_amdgcn_mfma_f32_16x16x32_f16(ax.h, bx.h, acc2a, 0, 0, 0);
            }
            f4 acc2 = acc2a + acc2b;
            // epilogue: gather (off_k, msk_k) per lane q=k (k=0..2), col r
            float b0 = __shfl(acc2[0], r);           // off0: q0.e0
            float b1 = __shfl(acc2[1], r);           // off1: q0.e1
            float b2 = __shfl(acc2[2], r);           // off2: q0.e2
            float m0 = __shfl(acc2[3], r);           // msk0: q0.e3
            float m1 = __shfl(acc2[0], 16 + r);      // msk1: q1.e0
            float m2 = __shfl(acc2[1], 16 + r);      // msk2: q1.e1
            if (q < 3) {
                const int k = q, l = wv * 16 + r;
                float off = (k == 0 ? b0 : k == 1 ? b1 : b2) + beff_l[k];
                float z   = (k == 0 ? m0 : k == 1 ? m1 : m2) + beff_l[3 + k];
                float msk = 1.0f / (1.0f + __expf(-z));
                float p = (float)(l0 + l - 1 + k) + off;   // ref op order
                float fl = floorf(p);
                int i0 = (int)fl, i1 = i0 + 1;
                float fr = p - fl;
                int li0 = i0 - l0 + HALO, li1 = li0 + 1;
                float w0 = (((unsigned)i0 < (unsigned)LX) && ((unsigned)li0 < (unsigned)XI)) ? (1.0f - fr) * msk : 0.0f;
                float w1 = (((unsigned)i1 < (unsigned)LX) && ((unsigned)li1 < (unsigned)XI)) ? fr * msk : 0.0f;
                li0 = min(max(li0, 0), XI - 2);            // rows li0, li0+1 both staged
                mywp = pkrtz(w0, w1);
                myli = li0;
            }
        }
        // no barrier: kl data is wave-local (shfl), xdw/A2l are read-only here

        // ---- phase 3 start: issue next x tile's global loads (rx live only
        //      across phase 3; dovetails with wfr which is now dead) ----
        if (tt + 1 < TPB) issue_x(l0 + LT);

        // ---- phase 3: out[o][l] = W2[o][(tap,c)] @ xs[(tap,c)][l], M=64 K=192 N=64 ----
        {
            const int lcol = wv * 16 + r;
            unsigned wpt[3]; int lit[3];
            #pragma unroll
            for (int tap = 0; tap < 3; ++tap) {
                wpt[tap] = __shfl(mywp, tap * 16 + r);
                lit[tap] = __shfl(myli, tap * 16 + r);
            }
            f4 acc[4];
            #pragma unroll
            for (int mt = 0; mt < 4; ++mt) acc[mt] = (f4){0.f, 0.f, 0.f, 0.f};
            const int sw = (r & 7) << 2;
            #pragma unroll
            for (int kk = 0; kk < 6; ++kk) {
                const int tap = kk >> 1;
                unsigned wp = wpt[tap];
                unsigned w00 = __builtin_amdgcn_perm(wp, wp, 0x01000100u);  // (w0,w0)
                unsigned w11 = __builtin_amdgcn_perm(wp, wp, 0x03020302u);  // (w1,w1)
                int li0 = lit[tap];
                int cp0 = ((kk & 1) << 4) + (q << 2);      // dword idx {0,4,...,28}
                int chunkL = cp0 >> 3;
                int o0 = li0 * XPD + ((((chunkL + li0) & 3) << 3) | (cp0 & 7));
                int o1 = (li0 + 1) * XPD + ((((chunkL + li0 + 1) & 3) << 3) | (cp0 & 7));
                u4 r0 = *(const u4*)&xdw[o0];
                u4 r1 = *(const u4*)&xdw[o1];
                u4 xs;
                #pragma unroll
                for (int d = 0; d < 4; ++d)
                    xs[d] = h2u(u2h(r0[d]) * u2h(w00) + u2h(r1[d]) * u2h(w11));
                union { u4 u; h8 h; } bfr; bfr.u = xs;
                #pragma unroll
                for (int mt = 0; mt < 4; ++mt) {
                    union { u4 u; h8 h; } af;
                    af.u = *(const u4*)&A2l[(mt * 16 + r) * 96 + ((kk * 16 + q * 4) ^ sw)];
                    acc[mt] = __builtin_amdgcn_mfma_f32_16x16x32_f16(af.h, bfr.h, acc[mt], 0, 0, 0);
                }
            }
            #pragma unroll
            for (int mt = 0; mt < 4; ++mt) {
                int ob = mt * 16 + 4 * q;     // D row o = mt*16 + 4q + e, col l = lcol
                float* op = out + ((size_t)b * 64 + ob) * LX + l0 + lcol;
                #pragma unroll
                for (int e = 0; e < 4; ++e)
                    op[(size_t)e * LX] = acc[mt][e] + bias_l[ob + e];
            }
        }

        // ---- inter-tile: publish prefetched x tile t+1 ----
        if (tt < TPB - 1) {
            BAR_RAW();                         // all xdw readers of tile tt done
            write_x();                         // waits vmcnt only for rx regs
            BAR_LGKM();                        // new xdw visible for next phase 2
        }
    }
}

extern "C" void kernel_launch(void* const* d_in, const int* in_sizes, int n_in,
                              void* d_out, int out_size, void* d_ws, size_t ws_size,
                              hipStream_t stream) {
    const float* x        = (const float*)d_in[0];
    const float* w_off_dw = (const float*)d_in[1];
    const float* b_off_dw = (const float*)d_in[2];
    const float* w_off_pw = (const float*)d_in[3];
    const float* b_off_pw = (const float*)d_in[4];
    const float* w_msk_dw = (const float*)d_in[5];
    const float* b_msk_dw = (const float*)d_in[6];
    const float* w_msk_pw = (const float*)d_in[7];
    const float* b_msk_pw = (const float*)d_in[8];
    const float* weight   = (const float*)d_in[9];
    const float* bias     = (const float*)d_in[10];
    float* out = (float*)d_out;

    short*    A2   = (short*)d_ws;                     // 24576 B
    float*    beff = (float*)((char*)d_ws + 24576);    // 24 B (padded to 32)
    unsigned* wcg  = (unsigned*)((char*)d_ws + 24608); // 14336 B

    hipLaunchKernelGGL(prep_kernel, dim3(49), dim3(256), 0, stream,
                       weight, b_off_pw, w_off_pw, b_off_dw, b_msk_pw, w_msk_pw, b_msk_dw,
                       w_off_dw, w_msk_dw, A2, beff, wcg);
    hipLaunchKernelGGL(deform_main, dim3(LX / (LT * TPB), NB), dim3(256), 0, stream,
                       x, bias, A2, beff, wcg, out);
}

// Round 5
// 157.711 us; speedup vs baseline: 1.2124x; 1.0501x over previous
//
#include <hip/hip_runtime.h>
#include <cstdint>

#define LX 16384
#define NB 16
#define LT 64
#define TPB 4                 // l-tiles per block; grid.x = LX/(LT*TPB) = 64
#define HALO 8
#define XI (LT + 2*HALO)      // 80 staged positions
#define XPD 36                // x row pitch in dwords (144 B, 16B-aligned; chunk-rotated)

typedef __attribute__((ext_vector_type(2))) _Float16 h2;
typedef __attribute__((ext_vector_type(8))) _Float16 h8;
typedef __attribute__((ext_vector_type(4))) unsigned u4;
typedef __attribute__((ext_vector_type(4))) float f4;

static __device__ __forceinline__ h2 u2h(unsigned u) {
    union { unsigned u; h2 h; } v; v.u = u; return v.h;
}
static __device__ __forceinline__ unsigned h2u(h2 h) {
    union { h2 h; unsigned u; } v; v.h = h; return v.u;
}
static __device__ __forceinline__ unsigned pkrtz(float a, float b) {
    auto r = __builtin_amdgcn_cvt_pkrtz(a, b);        // __fp16 ext_vector(2)
    union { decltype(r) h; unsigned u; } v; v.h = r;
    return v.u;
}

// raw barriers: __syncthreads() drains vmcnt(0) and would kill the x prefetch.
#define BAR_LGKM() do { asm volatile("s_waitcnt lgkmcnt(0)" ::: "memory"); \
                        __builtin_amdgcn_s_barrier();                      \
                        asm volatile("" ::: "memory"); } while (0)
#define BAR_RAW()  do { asm volatile("" ::: "memory");                     \
                        __builtin_amdgcn_s_barrier();                      \
                        asm volatile("" ::: "memory"); } while (0)

// ---------------- kernel 0: prep weights into ws (all f16) ----------------
// ws: A2 f16[64][192] @0 (24576 B)  A2[o*192 + tap*64 + c] = weight[o][c][tap]
//   | beff f32[6] @24576
//   | wcg u32[14*256] @24608 (14336 B): combined offset/mask conv weights,
//     pre-fragmented for mfma_f32_16x16x32_f16 A-operand.
//     step s, thread t (lane=t>>2, d=t&3): m=lane&15, q=lane>>4, j=s>>1,
//     c=(s&1)*32+q*8+2d : packs (W[m][c][j], W[m][c+1][j]),
//     W[m][c][j] = pw[m][c]*dw[c][j] (m<3: off branch, 3..5: msk, else 0)
__global__ void prep_kernel(const float* __restrict__ weight,
                            const float* __restrict__ b_off_pw, const float* __restrict__ w_off_pw,
                            const float* __restrict__ b_off_dw,
                            const float* __restrict__ b_msk_pw, const float* __restrict__ w_msk_pw,
                            const float* __restrict__ b_msk_dw,
                            const float* __restrict__ w_off_dw, const float* __restrict__ w_msk_dw,
                            short* __restrict__ A2, float* __restrict__ beff,
                            unsigned* __restrict__ wcg) {
    int bid = blockIdx.x;
    int t = threadIdx.x;
    if (bid < 48) {
        int idx = bid * 256 + t;                  // 0..12287 : A2[o][tap*64+c]
        int o = idx / 192;
        int rem = idx - o * 192;
        int tap = rem >> 6, c = rem & 63;
        union { _Float16 h; short s; } v;
        v.h = (_Float16)weight[o * 192 + c * 3 + tap];
        A2[idx] = v.s;
    } else {
        // combined offset/mask conv weights, A-fragment order
        int lane = t >> 2, d = t & 3;
        int m = lane & 15, qq = lane >> 4;
        #pragma unroll
        for (int s = 0; s < 14; ++s) {
            int j = s >> 1;
            int c = (s & 1) * 32 + qq * 8 + 2 * d;
            float w0 = 0.f, w1 = 0.f;
            if (m < 3) {
                w0 = w_off_pw[m * 64 + c]     * w_off_dw[c * 7 + j];
                w1 = w_off_pw[m * 64 + c + 1] * w_off_dw[(c + 1) * 7 + j];
            } else if (m < 6) {
                w0 = w_msk_pw[(m - 3) * 64 + c]     * w_msk_dw[c * 7 + j];
                w1 = w_msk_pw[(m - 3) * 64 + c + 1] * w_msk_dw[(c + 1) * 7 + j];
            }
            wcg[s * 256 + t] = pkrtz(w0, w1);
        }
        if (t < 6) {
            int br = t / 3, m3 = t % 3;
            const float* pw = br ? w_msk_pw : w_off_pw;
            const float* bd = br ? b_msk_dw : b_off_dw;
            const float* bp = br ? b_msk_pw : b_off_pw;
            float s = bp[m3];
            for (int c = 0; c < 64; ++c) s += pw[m3 * 64 + c] * bd[c];
            beff[t] = s;
        }
    }
}

// ---------------- main fused kernel ----------------
// Each block owns TPB=4 consecutive l-tiles (runtime loop, unroll 1: one
// ~7 KB tile body instead of 4 copies -> fits L1I, kills cold-dispatch
// penalty, and prevents cross-tile live-range merging). A2 staged once per
// block. The combined conv-weight A-fragments are reloaded from L2 per tile
// in TWO batches of 7 (28 regs peak, not 56): batch-2's pointer is laundered
// with a data dependence on batch-1's accumulator so the scheduler cannot
// hoist its loads (round 4 kept all 14 live -> ~8 dword/thread scratch
// spill, +8 MB on both FETCH and WRITE). x-tile prefetch rx (24 regs) is
// issued at the START of phase 3 (dovetails with wfr, which is phase-2
// only). Phase-2 outputs stay wave-local (regs + shfl): no ph2->ph3 barrier.
__launch_bounds__(256, 4)
__global__ void deform_main(const float* __restrict__ x,
                            const float* __restrict__ bias,
                            const short* __restrict__ A2,
                            const float* __restrict__ beff,
                            const unsigned* __restrict__ wcg,
                            float* __restrict__ out) {
    // x tile f16 [i][c], c-pairs as dwords; 8-dword chunks rotated by row: phys = (chunk + i) & 3
    __shared__ __align__(16) unsigned xdw[XI * XPD];        // 11520 B
    // A2 staged in LDS, XOR-swizzled: phys_dw = row*96 + (dw ^ ((row&7)<<2))
    __shared__ __align__(16) unsigned A2l[6144];            // 24576 B
    __shared__ float bias_l[64];                            // 256 B
    __shared__ float beff_l[8];                             // 32 B
    // total 36384 B -> 4 blocks/CU

    const int t = threadIdx.x;
    const int lane = t & 63;
    const int wv = t >> 6;
    const int r = lane & 15, q = lane >> 4;
    const int lbase = blockIdx.x * (LT * TPB);
    const int b = blockIdx.y;
    const float* xb = x + (size_t)b * (64 * LX);

    // register staging for the next x tile (issue in phase 3 / write at tile end)
    f4 rx0[3], rx1[3];

    auto issue_x = [&](int l0v) {
        #pragma unroll
        for (int s = 0; s < 3; ++s) {
            int p = t + 256 * s;
            rx0[s] = (f4){0.f, 0.f, 0.f, 0.f};
            rx1[s] = (f4){0.f, 0.f, 0.f, 0.f};
            if (p < 640) {
                int cp = p & 31, up = p >> 5;
                int g4 = l0v - HALO + up * 4;
                if ((unsigned)g4 < (unsigned)LX) {
                    rx0[s] = *(const f4*)(xb + (size_t)(2 * cp) * LX + g4);
                    rx1[s] = *(const f4*)(xb + (size_t)(2 * cp + 1) * LX + g4);
                }
            }
        }
    };
    auto write_x = [&]() {
        #pragma unroll
        for (int s = 0; s < 3; ++s) {
            int p = t + 256 * s;
            if (p < 640) {
                int cp = p & 31, up = p >> 5;
                #pragma unroll
                for (int d = 0; d < 4; ++d) {
                    int i = up * 4 + d;
                    int pc = ((cp >> 3) + i) & 3;
                    xdw[i * XPD + pc * 8 + (cp & 7)] = pkrtz(rx0[s][d], rx1[s][d]);
                }
            }
        }
    };

    // ---- prologue: issue x tile 0, stage block-constant data, write tile 0 ----
    issue_x(lbase);
    {
        const u4* A2g4 = (const u4*)A2;          // 1536 u4, coalesced 16B/lane
        #pragma unroll
        for (int s = 0; s < 6; ++s) {
            int idx = t + 256 * s;               // 0..1535
            int row = idx / 24;
            int g = idx - row * 24;
            int pdw = row * 96 + ((g * 4) ^ ((row & 7) << 2));
            *(u4*)&A2l[pdw] = A2g4[idx];
        }
    }
    if (t < 64) bias_l[t] = bias[t];
    if (t < 6)  beff_l[t] = beff[t];
    write_x();                                   // waits vmcnt for tile-0 loads
    BAR_LGKM();

    #pragma unroll 1
    for (int tt = 0; tt < TPB; ++tt) {
        const int l0 = lbase + tt * LT;

        // Laundered per-tile pointer: the 2x7 A-fragment loads cannot be
        // hoisted/CSE'd across tiles or batches.
        const u4* wcp = (const u4*)wcg;
        asm volatile("" : "+s"(wcp));

        // ---- phase 2: offset/mask conv as MFMA, M=16(6 used) K=448 N=16/wave ----
        // D row m (0..2 off, 3..5 msk), col l = wv*16 + (lane&15).
        // Two accumulator chains (7 deep each); A-fragments loaded in two
        // batches of 7 so only 28 weight regs are ever live.
        unsigned mywp = 0; int myli = 0;
        {
            f4 acc2a = {0.f, 0.f, 0.f, 0.f};
            f4 acc2b = {0.f, 0.f, 0.f, 0.f};
            const int irow = wv * 16 + r + 5;            // + j
            {
                u4 w7[7];
                #pragma unroll
                for (int s = 0; s < 7; ++s) w7[s] = wcp[s * 64 + lane];
                #pragma unroll
                for (int s = 0; s < 7; ++s) {
                    const int j = s >> 1, half = s & 1;
                    const int i = irow + j;
                    const int chunk = half * 2 + (q >> 1);
                    const int pd = i * XPD + (((chunk + i) & 3) << 3) + ((q & 1) << 2);
                    union { u4 u; h8 h; } bx; bx.u = *(const u4*)&xdw[pd];
                    union { u4 u; h8 h; } ax; ax.u = w7[s];
                    if (s & 1)
                        acc2b = __builtin_amdgcn_mfma_f32_16x16x32_f16(ax.h, bx.h, acc2b, 0, 0, 0);
                    else
                        acc2a = __builtin_amdgcn_mfma_f32_16x16x32_f16(ax.h, bx.h, acc2a, 0, 0, 0);
                }
            }
            // Batch-2 pointer depends on batch-1's last MFMA result (s=6 ->
            // acc2a): loads cannot be scheduled before batch-1 completes, so
            // the two w7 live ranges are disjoint.
            {
                float dep = acc2a[0];
                asm volatile("" : "+s"(wcp) : "v"(dep));
                u4 w7[7];
                #pragma unroll
                for (int s = 0; s < 7; ++s) w7[s] = wcp[(s + 7) * 64 + lane];
                #pragma unroll
                for (int s = 7; s < 14; ++s) {
                    const int j = s >> 1, half = s & 1;
                    const int i = irow + j;
                    const int chunk = half * 2 + (q >> 1);
                    const int pd = i * XPD + (((chunk + i) & 3) << 3) + ((q & 1) << 2);
                    union { u4 u; h8 h; } bx; bx.u = *(const u4*)&xdw[pd];
                    union { u4 u; h8 h; } ax; ax.u = w7[s - 7];
                    if (s & 1)
                        acc2b = __builtin_amdgcn_mfma_f32_16x16x32_f16(ax.h, bx.h, acc2b, 0, 0, 0);
                    else
                        acc2a = __builtin_amdgcn_mfma_f32_16x16x32_f16(ax.h, bx.h, acc2a, 0, 0, 0);
                }
            }
            f4 acc2 = acc2a + acc2b;
            // epilogue: gather (off_k, msk_k) per lane q=k (k=0..2), col r
            float b0 = __shfl(acc2[0], r);           // off0: q0.e0
            float b1 = __shfl(acc2[1], r);           // off1: q0.e1
            float b2 = __shfl(acc2[2], r);           // off2: q0.e2
            float m0 = __shfl(acc2[3], r);           // msk0: q0.e3
            float m1 = __shfl(acc2[0], 16 + r);      // msk1: q1.e0
            float m2 = __shfl(acc2[1], 16 + r);      // msk2: q1.e1
            if (q < 3) {
                const int k = q, l = wv * 16 + r;
                float off = (k == 0 ? b0 : k == 1 ? b1 : b2) + beff_l[k];
                float z   = (k == 0 ? m0 : k == 1 ? m1 : m2) + beff_l[3 + k];
                float msk = 1.0f / (1.0f + __expf(-z));
                float p = (float)(l0 + l - 1 + k) + off;   // ref op order
                float fl = floorf(p);
                int i0 = (int)fl, i1 = i0 + 1;
                float fr = p - fl;
                int li0 = i0 - l0 + HALO, li1 = li0 + 1;
                float w0 = (((unsigned)i0 < (unsigned)LX) && ((unsigned)li0 < (unsigned)XI)) ? (1.0f - fr) * msk : 0.0f;
                float w1 = (((unsigned)i1 < (unsigned)LX) && ((unsigned)li1 < (unsigned)XI)) ? fr * msk : 0.0f;
                li0 = min(max(li0, 0), XI - 2);            // rows li0, li0+1 both staged
                mywp = pkrtz(w0, w1);
                myli = li0;
            }
        }
        // no barrier: kl data is wave-local (shfl), xdw/A2l are read-only here

        // ---- phase 3 start: issue next x tile's global loads (rx live only
        //      across phase 3; dovetails with wfr which is now dead) ----
        if (tt + 1 < TPB) issue_x(l0 + LT);

        // ---- phase 3: out[o][l] = W2[o][(tap,c)] @ xs[(tap,c)][l], M=64 K=192 N=64 ----
        {
            const int lcol = wv * 16 + r;
            unsigned wpt[3]; int lit[3];
            #pragma unroll
            for (int tap = 0; tap < 3; ++tap) {
                wpt[tap] = __shfl(mywp, tap * 16 + r);
                lit[tap] = __shfl(myli, tap * 16 + r);
            }
            f4 acc[4];
            #pragma unroll
            for (int mt = 0; mt < 4; ++mt) acc[mt] = (f4){0.f, 0.f, 0.f, 0.f};
            const int sw = (r & 7) << 2;
            #pragma unroll
            for (int kk = 0; kk < 6; ++kk) {
                const int tap = kk >> 1;
                unsigned wp = wpt[tap];
                unsigned w00 = __builtin_amdgcn_perm(wp, wp, 0x01000100u);  // (w0,w0)
                unsigned w11 = __builtin_amdgcn_perm(wp, wp, 0x03020302u);  // (w1,w1)
                int li0 = lit[tap];
                int cp0 = ((kk & 1) << 4) + (q << 2);      // dword idx {0,4,...,28}
                int chunkL = cp0 >> 3;
                int o0 = li0 * XPD + ((((chunkL + li0) & 3) << 3) | (cp0 & 7));
                int o1 = (li0 + 1) * XPD + ((((chunkL + li0 + 1) & 3) << 3) | (cp0 & 7));
                u4 r0 = *(const u4*)&xdw[o0];
                u4 r1 = *(const u4*)&xdw[o1];
                u4 xs;
                #pragma unroll
                for (int d = 0; d < 4; ++d)
                    xs[d] = h2u(u2h(r0[d]) * u2h(w00) + u2h(r1[d]) * u2h(w11));
                union { u4 u; h8 h; } bfr; bfr.u = xs;
                #pragma unroll
                for (int mt = 0; mt < 4; ++mt) {
                    union { u4 u; h8 h; } af;
                    af.u = *(const u4*)&A2l[(mt * 16 + r) * 96 + ((kk * 16 + q * 4) ^ sw)];
                    acc[mt] = __builtin_amdgcn_mfma_f32_16x16x32_f16(af.h, bfr.h, acc[mt], 0, 0, 0);
                }
            }
            #pragma unroll
            for (int mt = 0; mt < 4; ++mt) {
                int ob = mt * 16 + 4 * q;     // D row o = mt*16 + 4q + e, col l = lcol
                float* op = out + ((size_t)b * 64 + ob) * LX + l0 + lcol;
                #pragma unroll
                for (int e = 0; e < 4; ++e)
                    op[(size_t)e * LX] = acc[mt][e] + bias_l[ob + e];
            }
        }

        // ---- inter-tile: publish prefetched x tile t+1 ----
        if (tt < TPB - 1) {
            BAR_RAW();                         // all xdw readers of tile tt done
            write_x();                         // waits vmcnt only for rx regs
            BAR_LGKM();                        // new xdw visible for next phase 2
        }
    }
}

extern "C" void kernel_launch(void* const* d_in, const int* in_sizes, int n_in,
                              void* d_out, int out_size, void* d_ws, size_t ws_size,
                              hipStream_t stream) {
    const float* x        = (const float*)d_in[0];
    const float* w_off_dw = (const float*)d_in[1];
    const float* b_off_dw = (const float*)d_in[2];
    const float* w_off_pw = (const float*)d_in[3];
    const float* b_off_pw = (const float*)d_in[4];
    const float* w_msk_dw = (const float*)d_in[5];
    const float* b_msk_dw = (const float*)d_in[6];
    const float* w_msk_pw = (const float*)d_in[7];
    const float* b_msk_pw = (const float*)d_in[8];
    const float* weight   = (const float*)d_in[9];
    const float* bias     = (const float*)d_in[10];
    float* out = (float*)d_out;

    short*    A2   = (short*)d_ws;                     // 24576 B
    float*    beff = (float*)((char*)d_ws + 24576);    // 24 B (padded to 32)
    unsigned* wcg  = (unsigned*)((char*)d_ws + 24608); // 14336 B

    hipLaunchKernelGGL(prep_kernel, dim3(49), dim3(256), 0, stream,
                       weight, b_off_pw, w_off_pw, b_off_dw, b_msk_pw, w_msk_pw, b_msk_dw,
                       w_off_dw, w_msk_dw, A2, beff, wcg);
    hipLaunchKernelGGL(deform_main, dim3(LX / (LT * TPB), NB), dim3(256), 0, stream,
                       x, bias, A2, beff, wcg, out);
}

// Round 6
// 149.432 us; speedup vs baseline: 1.2795x; 1.0554x over previous
//
#include <hip/hip_runtime.h>
#include <cstdint>

#define LX 16384
#define NB 16
#define LT 64
#define TPB 2                 // l-tiles per block; grid.x = LX/(LT*TPB) = 128
#define HALO 8
#define XI (LT + 2*HALO)      // 80 staged positions
#define XPD 36                // x row pitch in dwords (144 B, 16B-aligned; chunk-rotated)
#define XSZ (XI * XPD)        // one xdw buffer, dwords (11520 B)

typedef __attribute__((ext_vector_type(2))) _Float16 h2;
typedef __attribute__((ext_vector_type(8))) _Float16 h8;
typedef __attribute__((ext_vector_type(4))) unsigned u4;
typedef __attribute__((ext_vector_type(4))) float f4;

static __device__ __forceinline__ h2 u2h(unsigned u) {
    union { unsigned u; h2 h; } v; v.u = u; return v.h;
}
static __device__ __forceinline__ unsigned h2u(h2 h) {
    union { h2 h; unsigned u; } v; v.h = h; return v.u;
}
static __device__ __forceinline__ unsigned pkrtz(float a, float b) {
    auto r = __builtin_amdgcn_cvt_pkrtz(a, b);        // __fp16 ext_vector(2)
    union { decltype(r) h; unsigned u; } v; v.h = r;
    return v.u;
}

// raw barriers: __syncthreads() drains vmcnt(0) and would kill the x prefetch.
#define BAR_LGKM() do { asm volatile("s_waitcnt lgkmcnt(0)" ::: "memory"); \
                        __builtin_amdgcn_s_barrier();                      \
                        asm volatile("" ::: "memory"); } while (0)

// ---------------- kernel 0: prep weights into ws (all f16) ----------------
// ws: A2 f16[64][192] @0 (24576 B)  A2[o*192 + tap*64 + c] = weight[o][c][tap]
//   | beff f32[6] @24576
//   | wcg u32[14*256] @24608 (14336 B): combined offset/mask conv weights,
//     pre-fragmented for mfma_f32_16x16x32_f16 A-operand.
//     step s, thread t (lane=t>>2, d=t&3): m=lane&15, q=lane>>4, j=s>>1,
//     c=(s&1)*32+q*8+2d : packs (W[m][c][j], W[m][c+1][j]),
//     W[m][c][j] = pw[m][c]*dw[c][j] (m<3: off branch, 3..5: msk, else 0)
__global__ void prep_kernel(const float* __restrict__ weight,
                            const float* __restrict__ b_off_pw, const float* __restrict__ w_off_pw,
                            const float* __restrict__ b_off_dw,
                            const float* __restrict__ b_msk_pw, const float* __restrict__ w_msk_pw,
                            const float* __restrict__ b_msk_dw,
                            const float* __restrict__ w_off_dw, const float* __restrict__ w_msk_dw,
                            short* __restrict__ A2, float* __restrict__ beff,
                            unsigned* __restrict__ wcg) {
    int bid = blockIdx.x;
    int t = threadIdx.x;
    if (bid < 48) {
        int idx = bid * 256 + t;                  // 0..12287 : A2[o][tap*64+c]
        int o = idx / 192;
        int rem = idx - o * 192;
        int tap = rem >> 6, c = rem & 63;
        union { _Float16 h; short s; } v;
        v.h = (_Float16)weight[o * 192 + c * 3 + tap];
        A2[idx] = v.s;
    } else {
        // combined offset/mask conv weights, A-fragment order
        int lane = t >> 2, d = t & 3;
        int m = lane & 15, qq = lane >> 4;
        #pragma unroll
        for (int s = 0; s < 14; ++s) {
            int j = s >> 1;
            int c = (s & 1) * 32 + qq * 8 + 2 * d;
            float w0 = 0.f, w1 = 0.f;
            if (m < 3) {
                w0 = w_off_pw[m * 64 + c]     * w_off_dw[c * 7 + j];
                w1 = w_off_pw[m * 64 + c + 1] * w_off_dw[(c + 1) * 7 + j];
            } else if (m < 6) {
                w0 = w_msk_pw[(m - 3) * 64 + c]     * w_msk_dw[c * 7 + j];
                w1 = w_msk_pw[(m - 3) * 64 + c + 1] * w_msk_dw[(c + 1) * 7 + j];
            }
            wcg[s * 256 + t] = pkrtz(w0, w1);
        }
        if (t < 6) {
            int br = t / 3, m3 = t % 3;
            const float* pw = br ? w_msk_pw : w_off_pw;
            const float* bd = br ? b_msk_dw : b_off_dw;
            const float* bp = br ? b_msk_pw : b_off_pw;
            float s = bp[m3];
            for (int c = 0; c < 64; ++c) s += pw[m3 * 64 + c] * bd[c];
            beff[t] = s;
        }
    }
}

// ---------------- main fused kernel ----------------
// launch_bounds(256,3): 3 blocks/CU (12 waves) with a 170-VGPR budget.
// Measured effective occupancy of the (256,4) version was only ~11 waves/CU,
// so the theoretical drop 16->12 is ~free, and the register headroom buys:
//  - wfr[14] (56 regs) loaded ONCE per block, register-resident for the
//    whole kernel: no per-tile L2 reloads, no launder serialization bubbles
//    (round 5 paid ~2x200cy of L2 latency inside every phase 2).
//  - xdw DOUBLE-BUFFERED (+11.5 KB LDS -> 47.9 KB, inside the 53.3 KB
//    3-block budget): write_x targets the idle buffer, so the pre-write
//    barrier disappears -> ONE barrier per tile. (The previous tile's
//    end-of-tile lgkmcnt(0)+barrier already retired all reads of that
//    buffer, so overwriting it needs no extra sync.)
// TPB=2 (grid 2048 = 8 blocks/CU work, residency rounds 3+3+2) avoids the
// 3+1 tail imbalance TPB=4 would have at 3 blocks/CU.
__launch_bounds__(256, 3)
__global__ void deform_main(const float* __restrict__ x,
                            const float* __restrict__ bias,
                            const short* __restrict__ A2,
                            const float* __restrict__ beff,
                            const unsigned* __restrict__ wcg,
                            float* __restrict__ out) {
    // x tile f16 [i][c], c-pairs as dwords; 8-dword chunks rotated by row:
    // phys = (chunk + i) & 3. Two buffers (double-buffered across tiles).
    __shared__ __align__(16) unsigned xdw[2 * XSZ];         // 23040 B
    // A2 staged in LDS, XOR-swizzled: phys_dw = row*96 + (dw ^ ((row&7)<<2))
    __shared__ __align__(16) unsigned A2l[6144];            // 24576 B
    __shared__ float bias_l[64];                            // 256 B
    __shared__ float beff_l[8];                             // 32 B
    // total 47904 B -> 3 blocks/CU

    const int t = threadIdx.x;
    const int lane = t & 63;
    const int wv = t >> 6;
    const int r = lane & 15, q = lane >> 4;
    const int lbase = blockIdx.x * (LT * TPB);
    const int b = blockIdx.y;
    const float* xb = x + (size_t)b * (64 * LX);

    // register staging for the next x tile (issue in phase 3 / write at tile end)
    f4 rx0[3], rx1[3];

    auto issue_x = [&](int l0v) {
        #pragma unroll
        for (int s = 0; s < 3; ++s) {
            int p = t + 256 * s;
            rx0[s] = (f4){0.f, 0.f, 0.f, 0.f};
            rx1[s] = (f4){0.f, 0.f, 0.f, 0.f};
            if (p < 640) {
                int cp = p & 31, up = p >> 5;
                int g4 = l0v - HALO + up * 4;
                if ((unsigned)g4 < (unsigned)LX) {
                    rx0[s] = *(const f4*)(xb + (size_t)(2 * cp) * LX + g4);
                    rx1[s] = *(const f4*)(xb + (size_t)(2 * cp + 1) * LX + g4);
                }
            }
        }
    };
    auto write_x = [&](unsigned base) {
        #pragma unroll
        for (int s = 0; s < 3; ++s) {
            int p = t + 256 * s;
            if (p < 640) {
                int cp = p & 31, up = p >> 5;
                #pragma unroll
                for (int d = 0; d < 4; ++d) {
                    int i = up * 4 + d;
                    int pc = ((cp >> 3) + i) & 3;
                    xdw[base + i * XPD + pc * 8 + (cp & 7)] = pkrtz(rx0[s][d], rx1[s][d]);
                }
            }
        }
    };

    // ---- prologue: issue x tile 0, stage A2, load weight fragments (kept
    //      in registers for the whole kernel), write tile 0 into buf 0 ----
    issue_x(lbase);
    {
        const u4* A2g4 = (const u4*)A2;          // 1536 u4, coalesced 16B/lane
        #pragma unroll
        for (int s = 0; s < 6; ++s) {
            int idx = t + 256 * s;               // 0..1535
            int row = idx / 24;
            int g = idx - row * 24;
            int pdw = row * 96 + ((g * 4) ^ ((row & 7) << 2));
            *(u4*)&A2l[pdw] = A2g4[idx];
        }
    }
    u4 wfr[14];
    {
        const u4* wc4 = (const u4*)wcg;
        #pragma unroll
        for (int s = 0; s < 14; ++s) wfr[s] = wc4[s * 64 + lane];
    }
    if (t < 64) bias_l[t] = bias[t];
    if (t < 6)  beff_l[t] = beff[t];
    write_x(0);                                  // waits vmcnt for tile-0 loads
    BAR_LGKM();

    #pragma unroll
    for (int tt = 0; tt < TPB; ++tt) {
        const int l0 = lbase + tt * LT;
        const unsigned cur = (unsigned)(tt & 1) * XSZ;
        const unsigned nxt = (unsigned)((tt + 1) & 1) * XSZ;

        // ---- phase 2: offset/mask conv as MFMA, M=16(6 used) K=448 N=16/wave ----
        // D row m (0..2 off, 3..5 msk), col l = wv*16 + (lane&15).
        // Two accumulator chains (7 deep each) halve the serial MFMA latency.
        unsigned mywp = 0; int myli = 0;
        {
            f4 acc2a = {0.f, 0.f, 0.f, 0.f};
            f4 acc2b = {0.f, 0.f, 0.f, 0.f};
            const int irow = wv * 16 + r + 5;            // + j
            #pragma unroll
            for (int s = 0; s < 14; ++s) {
                const int j = s >> 1, half = s & 1;
                const int i = irow + j;
                const int chunk = half * 2 + (q >> 1);
                const int pd = cur + i * XPD + (((chunk + i) & 3) << 3) + ((q & 1) << 2);
                union { u4 u; h8 h; } bx; bx.u = *(const u4*)&xdw[pd];
                union { u4 u; h8 h; } ax; ax.u = wfr[s];
                if (s & 1)
                    acc2b = __builtin_amdgcn_mfma_f32_16x16x32_f16(ax.h, bx.h, acc2b, 0, 0, 0);
                else
                    acc2a = __builtin_amdgcn_mfma_f32_16x16x32_f16(ax.h, bx.h, acc2a, 0, 0, 0);
            }
            f4 acc2 = acc2a + acc2b;
            // epilogue: gather (off_k, msk_k) per lane q=k (k=0..2), col r
            float b0 = __shfl(acc2[0], r);           // off0: q0.e0
            float b1 = __shfl(acc2[1], r);           // off1: q0.e1
            float b2 = __shfl(acc2[2], r);           // off2: q0.e2
            float m0 = __shfl(acc2[3], r);           // msk0: q0.e3
            float m1 = __shfl(acc2[0], 16 + r);      // msk1: q1.e0
            float m2 = __shfl(acc2[1], 16 + r);      // msk2: q1.e1
            if (q < 3) {
                const int k = q, l = wv * 16 + r;
                float off = (k == 0 ? b0 : k == 1 ? b1 : b2) + beff_l[k];
                float z   = (k == 0 ? m0 : k == 1 ? m1 : m2) + beff_l[3 + k];
                float msk = 1.0f / (1.0f + __expf(-z));
                float p = (float)(l0 + l - 1 + k) + off;   // ref op order
                float fl = floorf(p);
                int i0 = (int)fl, i1 = i0 + 1;
                float fr = p - fl;
                int li0 = i0 - l0 + HALO, li1 = li0 + 1;
                float w0 = (((unsigned)i0 < (unsigned)LX) && ((unsigned)li0 < (unsigned)XI)) ? (1.0f - fr) * msk : 0.0f;
                float w1 = (((unsigned)i1 < (unsigned)LX) && ((unsigned)li1 < (unsigned)XI)) ? fr * msk : 0.0f;
                li0 = min(max(li0, 0), XI - 2);            // rows li0, li0+1 both staged
                mywp = pkrtz(w0, w1);
                myli = li0;
            }
        }
        // no barrier: kl data is wave-local (shfl), xdw/A2l are read-only here

        // ---- phase 3 start: issue next x tile's global loads (HBM latency
        //      hides under phase 3's MFMA + stores) ----
        if (tt + 1 < TPB) issue_x(l0 + LT);

        // ---- phase 3: out[o][l] = W2[o][(tap,c)] @ xs[(tap,c)][l], M=64 K=192 N=64 ----
        {
            const int lcol = wv * 16 + r;
            unsigned wpt[3]; int lit[3];
            #pragma unroll
            for (int tap = 0; tap < 3; ++tap) {
                wpt[tap] = __shfl(mywp, tap * 16 + r);
                lit[tap] = __shfl(myli, tap * 16 + r);
            }
            f4 acc[4];
            #pragma unroll
            for (int mt = 0; mt < 4; ++mt) acc[mt] = (f4){0.f, 0.f, 0.f, 0.f};
            const int sw = (r & 7) << 2;
            #pragma unroll
            for (int kk = 0; kk < 6; ++kk) {
                const int tap = kk >> 1;
                unsigned wp = wpt[tap];
                unsigned w00 = __builtin_amdgcn_perm(wp, wp, 0x01000100u);  // (w0,w0)
                unsigned w11 = __builtin_amdgcn_perm(wp, wp, 0x03020302u);  // (w1,w1)
                int li0 = lit[tap];
                int cp0 = ((kk & 1) << 4) + (q << 2);      // dword idx {0,4,...,28}
                int chunkL = cp0 >> 3;
                int o0 = cur + li0 * XPD + ((((chunkL + li0) & 3) << 3) | (cp0 & 7));
                int o1 = cur + (li0 + 1) * XPD + ((((chunkL + li0 + 1) & 3) << 3) | (cp0 & 7));
                u4 r0 = *(const u4*)&xdw[o0];
                u4 r1 = *(const u4*)&xdw[o1];
                u4 xs;
                #pragma unroll
                for (int d = 0; d < 4; ++d)
                    xs[d] = h2u(u2h(r0[d]) * u2h(w00) + u2h(r1[d]) * u2h(w11));
                union { u4 u; h8 h; } bfr; bfr.u = xs;
                #pragma unroll
                for (int mt = 0; mt < 4; ++mt) {
                    union { u4 u; h8 h; } af;
                    af.u = *(const u4*)&A2l[(mt * 16 + r) * 96 + ((kk * 16 + q * 4) ^ sw)];
                    acc[mt] = __builtin_amdgcn_mfma_f32_16x16x32_f16(af.h, bfr.h, acc[mt], 0, 0, 0);
                }
            }
            #pragma unroll
            for (int mt = 0; mt < 4; ++mt) {
                int ob = mt * 16 + 4 * q;     // D row o = mt*16 + 4q + e, col l = lcol
                float* op = out + ((size_t)b * 64 + ob) * LX + l0 + lcol;
                #pragma unroll
                for (int e = 0; e < 4; ++e)
                    op[(size_t)e * LX] = acc[mt][e] + bias_l[ob + e];
            }
        }

        // ---- inter-tile: publish prefetched x tile t+1 into the idle buffer.
        // No pre-barrier needed: buf `nxt`'s last readers were tile t-1's
        // phases, already retired at the previous BAR_LGKM. ----
        if (tt < TPB - 1) {
            write_x(nxt);                      // waits vmcnt only for rx regs
            BAR_LGKM();                        // new xdw visible for next phase 2
        }
    }
}

extern "C" void kernel_launch(void* const* d_in, const int* in_sizes, int n_in,
                              void* d_out, int out_size, void* d_ws, size_t ws_size,
                              hipStream_t stream) {
    const float* x        = (const float*)d_in[0];
    const float* w_off_dw = (const float*)d_in[1];
    const float* b_off_dw = (const float*)d_in[2];
    const float* w_off_pw = (const float*)d_in[3];
    const float* b_off_pw = (const float*)d_in[4];
    const float* w_msk_dw = (const float*)d_in[5];
    const float* b_msk_dw = (const float*)d_in[6];
    const float* w_msk_pw = (const float*)d_in[7];
    const float* b_msk_pw = (const float*)d_in[8];
    const float* weight   = (const float*)d_in[9];
    const float* bias     = (const float*)d_in[10];
    float* out = (float*)d_out;

    short*    A2   = (short*)d_ws;                     // 24576 B
    float*    beff = (float*)((char*)d_ws + 24576);    // 24 B (padded to 32)
    unsigned* wcg  = (unsigned*)((char*)d_ws + 24608); // 14336 B

    hipLaunchKernelGGL(prep_kernel, dim3(49), dim3(256), 0, stream,
                       weight, b_off_pw, w_off_pw, b_off_dw, b_msk_pw, w_msk_pw, b_msk_dw,
                       w_off_dw, w_msk_dw, A2, beff, wcg);
    hipLaunchKernelGGL(deform_main, dim3(LX / (LT * TPB), NB), dim3(256), 0, stream,
                       x, bias, A2, beff, wcg, out);
}